// Round 6
// baseline (4271.437 us; speedup 1.0000x reference)
//
#include <hip/hip_runtime.h>
#include <hip/hip_bf16.h>
#include <math.h>

// ---- problem constants ----
#define DIMC 192
#define NTOK 343
#define NHEADS 6
#define HD 32
#define NN 117649           // NTOK*NTOK
#define MLP 768
#define MTOT 43904
#define QSCALE 0.17677669529663687f

// fixed ws region: fp32 bias [6][343][343] = 2,823,576 B (rounded up)
#define WS_AFTER_BIAS 2823680

__device__ __forceinline__ float b2f(__hip_bfloat16 v) { return __bfloat162float(v); }
__device__ __forceinline__ __hip_bfloat16 f2b(float v) { return __float2bfloat16(v); }
__device__ __forceinline__ float ldf(const float* p) { return *p; }
__device__ __forceinline__ float ldf(const __hip_bfloat16* p) { return b2f(*p); }

__device__ __forceinline__ float2 bfp2(unsigned u) {
    union { unsigned i; float f; } a, b;
    a.i = u << 16;
    b.i = u & 0xffff0000u;
    return make_float2(a.f, b.f);
}

// (global window, token-in-window) -> linear token index in x (handles cyclic shift)
__device__ __forceinline__ int win_to_tok(int w, int n) {
    int bb = w >> 6, widx = w & 63;
    int wd = widx >> 4, wh = (widx >> 2) & 3, ww = widx & 3;
    int sd = n / 49, r = n - sd * 49;
    int sh = r / 7, sw = r - sh * 7;
    int gd = wd * 7 + sd + 3; if (gd >= 28) gd -= 28;
    int gh = wh * 7 + sh + 3; if (gh >= 28) gh -= 28;
    int gw = ww * 7 + sw + 3; if (gw >= 28) gw -= 28;
    return bb * 21952 + gd * 784 + gh * 28 + gw;
}

// ---------------- rel-position bias gather: biasT[h][n][m] fp32 ----------------
__global__ __launch_bounds__(256) void bias_kernel(
    const int* __restrict__ rel, const float* __restrict__ table,
    float* __restrict__ biasT) {
    int idx = blockIdx.x * 256 + threadIdx.x;
    if (idx >= NN) return;
    int ri = rel[idx];
    #pragma unroll
    for (int h = 0; h < NHEADS; h++)
        biasT[(size_t)h * NN + idx] = table[ri * NHEADS + h];
}

// ---------------- LN1 + shift + window partition for one chunk (fp32 out) ----------------
__global__ __launch_bounds__(256) void ln1_kernel(
    const float* __restrict__ x, const float* __restrict__ g,
    const float* __restrict__ bt, float* __restrict__ wins,
    int w0, int Mrows) {
    int t = blockIdx.x * 4 + (threadIdx.x >> 6);   // local row in chunk
    if (t >= Mrows) return;
    int lane = threadIdx.x & 63;
    int wl = t / NTOK, n = t - wl * NTOK;
    int tok = win_to_tok(w0 + wl, n);
    const float* xp = x + (size_t)tok * DIMC;
    float v0 = xp[lane], v1 = xp[lane + 64], v2 = xp[lane + 128];
    float s = v0 + v1 + v2, s2 = v0 * v0 + v1 * v1 + v2 * v2;
    #pragma unroll
    for (int m = 32; m >= 1; m >>= 1) { s += __shfl_xor(s, m, 64); s2 += __shfl_xor(s2, m, 64); }
    float mean = s * (1.f / 192.f);
    float var = s2 * (1.f / 192.f) - mean * mean;
    float r = rsqrtf(var + 1e-5f);
    float* op = wins + (size_t)t * DIMC;
    op[lane]       = (v0 - mean) * r * g[lane]       + bt[lane];
    op[lane + 64]  = (v1 - mean) * r * g[lane + 64]  + bt[lane + 64];
    op[lane + 128] = (v2 - mean) * r * g[lane + 128] + bt[lane + 128];
}

// ---------------- LN2 for one MLP chunk (fp32 x2 input from d_out, fp32 out) ----------------
__global__ __launch_bounds__(256) void ln2_kernel(
    const float* __restrict__ x2, const float* __restrict__ g,
    const float* __restrict__ bt, float* __restrict__ y, int r0g) {
    int t = blockIdx.x * 4 + (threadIdx.x >> 6);   // local row
    int lane = threadIdx.x & 63;
    const float* xp = x2 + (size_t)(r0g + t) * DIMC;
    float v0 = xp[lane], v1 = xp[lane + 64], v2 = xp[lane + 128];
    float s = v0 + v1 + v2, s2 = v0 * v0 + v1 * v1 + v2 * v2;
    #pragma unroll
    for (int m = 32; m >= 1; m >>= 1) { s += __shfl_xor(s, m, 64); s2 += __shfl_xor(s2, m, 64); }
    float mean = s * (1.f / 192.f);
    float var = s2 * (1.f / 192.f) - mean * mean;
    float r = rsqrtf(var + 1e-5f);
    float* op = y + (size_t)t * DIMC;
    op[lane]       = (v0 - mean) * r * g[lane]       + bt[lane];
    op[lane + 64]  = (v1 - mean) * r * g[lane + 64]  + bt[lane + 64];
    op[lane + 128] = (v2 - mean) * r * g[lane + 128] + bt[lane + 128];
}

// ---------------- tiled GEMM: C[Mrows,N] = A[Mrows,K] * W[N,K]^T(fp32) + bias ----------------
// EPI 0: qkv scatter (+q scale) -> bf16 qkv    1: proj + shortcut -> fp32 d_out (token scatter)
//     2: GELU -> fp32 hid                      3: + x2(d_out) -> fp32 d_out in place
template <int EPI, typename AT>
__global__ __launch_bounds__(256) void gemm_kernel(
    const AT* __restrict__ A, const float* __restrict__ Bw,
    const float* __restrict__ bias, int K, int Mrows, int w0, int r0g,
    const float* __restrict__ shortcut,            // EPI1: original x (fp32)
    float* __restrict__ xout,                      // EPI1/EPI3: fp32 d_out
    void* __restrict__ out_p) {                    // EPI0: bf16 qkv, EPI2: fp32 hid
    __shared__ __align__(16) float As[16 * 64];
    __shared__ __align__(16) float Bs[16 * 64];
    int tid = threadIdx.x;
    int tx = tid & 15, ty = tid >> 4;
    int row0 = blockIdx.y * 64, col0 = blockIdx.x * 64;
    float acc[4][4];
    #pragma unroll
    for (int i = 0; i < 4; i++)
        #pragma unroll
        for (int j = 0; j < 4; j++) acc[i][j] = 0.f;
    int arow = tid >> 2, ak = (tid & 3) * 4;
    int ar = row0 + arow; if (ar >= Mrows) ar = Mrows - 1;   // clamp (dup row, never OOB)
    for (int k0 = 0; k0 < K; k0 += 16) {
        const AT* ap = A + (size_t)ar * K + k0 + ak;
        const float* bp = Bw + (size_t)(col0 + arow) * K + k0 + ak;
        #pragma unroll
        for (int e = 0; e < 4; e++) As[(ak + e) * 64 + arow] = ldf(ap + e);
        #pragma unroll
        for (int e = 0; e < 4; e++) Bs[(ak + e) * 64 + arow] = bp[e];
        __syncthreads();
        #pragma unroll
        for (int kk = 0; kk < 16; kk++) {
            float4 a4 = *(const float4*)&As[kk * 64 + ty * 4];
            float4 b4 = *(const float4*)&Bs[kk * 64 + tx * 4];
            float a[4] = {a4.x, a4.y, a4.z, a4.w};
            float b[4] = {b4.x, b4.y, b4.z, b4.w};
            #pragma unroll
            for (int i = 0; i < 4; i++)
                #pragma unroll
                for (int j = 0; j < 4; j++) acc[i][j] += a[i] * b[j];
        }
        __syncthreads();
    }
    #pragma unroll
    for (int i = 0; i < 4; i++) {
        int r = row0 + ty * 4 + i;   // local row
        if (r >= Mrows) continue;
        #pragma unroll
        for (int j = 0; j < 4; j++) {
            int c = col0 + tx * 4 + j;
            float v = acc[i][j] + bias[c];
            if (EPI == 0) {
                int wl = r / NTOK, n = r - wl * NTOK;
                int t = c / DIMC, rem = c - t * DIMC;
                int hh = rem >> 5, d = rem & 31;
                if (t == 0) v *= QSCALE;
                ((__hip_bfloat16*)out_p)[((((size_t)wl * NHEADS + hh) * 3 + t) * NTOK + n) * HD + d] = f2b(v);
            } else if (EPI == 1) {
                int wl = r / NTOK, n = r - wl * NTOK;
                size_t tok = (size_t)win_to_tok(w0 + wl, n);
                xout[tok * DIMC + c] = v + shortcut[tok * DIMC + c];
            } else if (EPI == 2) {
                float gel = 0.5f * v * (1.0f + erff(v * 0.70710678118654752f));
                ((float*)out_p)[(size_t)r * MLP + c] = gel;
            } else {
                size_t gi = (size_t)(r0g + r) * DIMC + c;
                xout[gi] += v;
            }
        }
    }
}

// ---------------- attention: one block per (local window, head) ----------------
// qkv chunk layout: [wl][h][t][n][d] bf16.  out: fp32 R0[(wl*343+n)*192 + h*32+d]
// mask indexed by global window within batch: (w0+wl) & 63
__global__ __launch_bounds__(384) void attn_kernel(
    const __hip_bfloat16* __restrict__ qkv, const float* __restrict__ biasT,
    const float* __restrict__ mask, float* __restrict__ out, int w0) {
    int blk = blockIdx.x;
    int wl = blk / NHEADS, h = blk - wl * NHEADS;
    int wm = (w0 + wl) & 63;
    __shared__ __align__(16) unsigned KsU[NTOK * 16];   // 21,952 B
    __shared__ __align__(16) unsigned VsU[NTOK * 16];   // 21,952 B
    const __hip_bfloat16* base = qkv + ((size_t)(wl * NHEADS + h) * 3) * NTOK * HD;
    const unsigned* kg = (const unsigned*)(base + NTOK * HD);
    const unsigned* vg = (const unsigned*)(base + 2 * NTOK * HD);
    for (int i = threadIdx.x; i < NTOK * 16; i += 384) { KsU[i] = kg[i]; VsU[i] = vg[i]; }
    __syncthreads();
    int n = threadIdx.x;
    if (n >= NTOK) return;
    float q[32];
    {
        const uint4* qg = (const uint4*)((const unsigned*)base + n * 16);
        #pragma unroll
        for (int v4 = 0; v4 < 4; v4++) {
            uint4 u = qg[v4];
            float2 p0 = bfp2(u.x), p1 = bfp2(u.y), p2 = bfp2(u.z), p3 = bfp2(u.w);
            q[v4 * 8 + 0] = p0.x; q[v4 * 8 + 1] = p0.y;
            q[v4 * 8 + 2] = p1.x; q[v4 * 8 + 3] = p1.y;
            q[v4 * 8 + 4] = p2.x; q[v4 * 8 + 5] = p2.y;
            q[v4 * 8 + 6] = p3.x; q[v4 * 8 + 7] = p3.y;
        }
    }
    const float* brow = biasT + ((size_t)h * NTOK + n) * NTOK;
    const float* mrow = mask + ((size_t)wm * NTOK + n) * NTOK;
    float smax = -1e30f;
    for (int m = 0; m < NTOK; m++) {
        const uint4* kr = (const uint4*)(KsU + m * 16);
        float s = 0.f;
        #pragma unroll
        for (int v4 = 0; v4 < 4; v4++) {
            uint4 u = kr[v4];
            float2 p0 = bfp2(u.x), p1 = bfp2(u.y), p2 = bfp2(u.z), p3 = bfp2(u.w);
            s += q[v4 * 8 + 0] * p0.x + q[v4 * 8 + 1] * p0.y
               + q[v4 * 8 + 2] * p1.x + q[v4 * 8 + 3] * p1.y
               + q[v4 * 8 + 4] * p2.x + q[v4 * 8 + 5] * p2.y
               + q[v4 * 8 + 6] * p3.x + q[v4 * 8 + 7] * p3.y;
        }
        s += brow[m] + mrow[m];
        smax = fmaxf(smax, s);
    }
    float l = 0.f;
    float acc[32];
    #pragma unroll
    for (int d = 0; d < 32; d++) acc[d] = 0.f;
    for (int m = 0; m < NTOK; m++) {
        const uint4* kr = (const uint4*)(KsU + m * 16);
        float s = 0.f;
        #pragma unroll
        for (int v4 = 0; v4 < 4; v4++) {
            uint4 u = kr[v4];
            float2 p0 = bfp2(u.x), p1 = bfp2(u.y), p2 = bfp2(u.z), p3 = bfp2(u.w);
            s += q[v4 * 8 + 0] * p0.x + q[v4 * 8 + 1] * p0.y
               + q[v4 * 8 + 2] * p1.x + q[v4 * 8 + 3] * p1.y
               + q[v4 * 8 + 4] * p2.x + q[v4 * 8 + 5] * p2.y
               + q[v4 * 8 + 6] * p3.x + q[v4 * 8 + 7] * p3.y;
        }
        s += brow[m] + mrow[m];
        float p = __expf(s - smax);
        l += p;
        const uint4* vr = (const uint4*)(VsU + m * 16);
        #pragma unroll
        for (int v4 = 0; v4 < 4; v4++) {
            uint4 u = vr[v4];
            float2 p0 = bfp2(u.x), p1 = bfp2(u.y), p2 = bfp2(u.z), p3 = bfp2(u.w);
            acc[v4 * 8 + 0] += p * p0.x; acc[v4 * 8 + 1] += p * p0.y;
            acc[v4 * 8 + 2] += p * p1.x; acc[v4 * 8 + 3] += p * p1.y;
            acc[v4 * 8 + 4] += p * p2.x; acc[v4 * 8 + 5] += p * p2.y;
            acc[v4 * 8 + 6] += p * p3.x; acc[v4 * 8 + 7] += p * p3.y;
        }
    }
    float rl = 1.f / l;
    float* orow = out + ((size_t)wl * NTOK + n) * DIMC + h * HD;
    #pragma unroll
    for (int d = 0; d < 32; d++) orow[d] = acc[d] * rl;
}

extern "C" void kernel_launch(void* const* d_in, const int* in_sizes, int n_in,
                              void* d_out, int out_size, void* d_ws, size_t ws_size,
                              hipStream_t stream) {
    const float* x      = (const float*)d_in[0];
    const float* mask   = (const float*)d_in[1];
    const int*   relidx = (const int*)d_in[2];
    const float* table  = (const float*)d_in[3];
    const float* n1g    = (const float*)d_in[4];
    const float* n1b    = (const float*)d_in[5];
    const float* qkv_w  = (const float*)d_in[6];
    const float* qkv_b  = (const float*)d_in[7];
    const float* proj_w = (const float*)d_in[8];
    const float* proj_b = (const float*)d_in[9];
    const float* n2g    = (const float*)d_in[10];
    const float* n2b    = (const float*)d_in[11];
    const float* fc1_w  = (const float*)d_in[12];
    const float* fc1_b  = (const float*)d_in[13];
    const float* fc2_w  = (const float*)d_in[14];
    const float* fc2_b  = (const float*)d_in[15];

    char* ws = (char*)d_ws;
    float* biasT = (float*)ws;
    float* out = (float*)d_out;          // fp32 output == residual stream x2

    // ---- ws_size-adaptive chunk sizes ----
    // attention: W windows/chunk; per window: R0 fp32 263,424 B + qkv bf16 395,136 B = 658,560 B
    int W = 1;
    {
        const int cand[5] = {16, 8, 4, 2, 1};
        for (int i = 0; i < 5; i++) {
            if ((size_t)WS_AFTER_BIAS + (size_t)cand[i] * 658560 <= ws_size) { W = cand[i]; break; }
        }
    }
    // mlp: R rows/chunk; per row: Y fp32 768 B + hid fp32 3072 B = 3840 B
    int R = 64;
    {
        const int cand[6] = {6272, 3136, 896, 448, 128, 64};
        for (int i = 0; i < 6; i++) {
            if ((size_t)WS_AFTER_BIAS + (size_t)cand[i] * 3840 <= ws_size) { R = cand[i]; break; }
        }
    }
    float*          R0  = (float*)(ws + WS_AFTER_BIAS);                                // W*263,424 B
    __hip_bfloat16* QKV = (__hip_bfloat16*)(ws + WS_AFTER_BIAS + (size_t)W * 263424);  // W*395,136 B
    float*          Y   = (float*)(ws + WS_AFTER_BIAS);                                // R*768 B (MLP phase)
    float*          HID = (float*)(ws + WS_AFTER_BIAS + (size_t)R * 768);              // R*3072 B

    bias_kernel<<<(NN + 255) / 256, 256, 0, stream>>>(relidx, table, biasT);

    // ---- attention path ----
    int mch = W * NTOK;                 // rows per chunk
    int gy = (mch + 63) / 64;
    int gln = (mch + 3) / 4;
    for (int c = 0; c < 128 / W; c++) {
        int w0 = c * W;
        ln1_kernel<<<gln, 256, 0, stream>>>(x, n1g, n1b, R0, w0, mch);
        gemm_kernel<0, float><<<dim3(9, gy), 256, 0, stream>>>(
            R0, qkv_w, qkv_b, DIMC, mch, w0, 0, nullptr, nullptr, QKV);
        attn_kernel<<<W * NHEADS, 384, 0, stream>>>(QKV, biasT, mask, R0, w0);
        gemm_kernel<1, float><<<dim3(3, gy), 256, 0, stream>>>(
            R0, proj_w, proj_b, DIMC, mch, w0, 0, x, out, nullptr);
    }

    // ---- MLP path ----
    for (int m = 0; m < MTOT / R; m++) {
        int r0g = m * R;
        ln2_kernel<<<R / 4, 256, 0, stream>>>(out, n2g, n2b, Y, r0g);
        gemm_kernel<2, float><<<dim3(12, R / 64), 256, 0, stream>>>(
            Y, fc1_w, fc1_b, DIMC, R, 0, 0, nullptr, nullptr, HID);
        gemm_kernel<3, float><<<dim3(3, R / 64), 256, 0, stream>>>(
            HID, fc2_w, fc2_b, MLP, R, 0, r0g, nullptr, out, nullptr);
    }
}

// Round 7
// 1324.050 us; speedup vs baseline: 3.2260x; 3.2260x over previous
//
#include <hip/hip_runtime.h>
#include <hip/hip_bf16.h>
#include <math.h>

// ---- problem constants ----
#define DIMC 192
#define NTOK 343
#define NHEADS 6
#define HD 32
#define NN 117649           // NTOK*NTOK
#define MLP 768
#define MTOT 43904
#define QSCALE 0.17677669529663687f

// fixed ws region: fp32 biasTT [6][343][343] = 2,823,576 B (rounded up)
#define WS_AFTER_BIAS 2823680

typedef __attribute__((ext_vector_type(8))) short bf16x8;
typedef __attribute__((ext_vector_type(4))) float f32x4;

__device__ __forceinline__ float b2f(__hip_bfloat16 v) { return __bfloat162float(v); }
__device__ __forceinline__ __hip_bfloat16 f2b(float v) { return __float2bfloat16(v); }
__device__ __forceinline__ float ldf(const float* p) { return *p; }
__device__ __forceinline__ float ldf(const __hip_bfloat16* p) { return b2f(*p); }
__device__ __forceinline__ unsigned short bfu(float v) {
    __hip_bfloat16 b = f2b(v);
    return *(unsigned short*)&b;
}

// (global window, token-in-window) -> linear token index in x (handles cyclic shift)
__device__ __forceinline__ int win_to_tok(int w, int n) {
    int bb = w >> 6, widx = w & 63;
    int wd = widx >> 4, wh = (widx >> 2) & 3, ww = widx & 3;
    int sd = n / 49, r = n - sd * 49;
    int sh = r / 7, sw = r - sh * 7;
    int gd = wd * 7 + sd + 3; if (gd >= 28) gd -= 28;
    int gh = wh * 7 + sh + 3; if (gh >= 28) gh -= 28;
    int gw = ww * 7 + sw + 3; if (gw >= 28) gw -= 28;
    return bb * 21952 + gd * 784 + gh * 28 + gw;
}

// ---------------- rel-position bias gather, TRANSPOSED: biasTT[h][m][q] fp32 ----------------
__global__ __launch_bounds__(256) void bias_kernel(
    const int* __restrict__ rel, const float* __restrict__ table,
    float* __restrict__ biasTT) {
    int idx = blockIdx.x * 256 + threadIdx.x;   // idx = m*343 + q
    if (idx >= NN) return;
    int m = idx / NTOK, q = idx - m * NTOK;
    int ri = rel[q * NTOK + m];
    #pragma unroll
    for (int h = 0; h < NHEADS; h++)
        biasTT[(size_t)h * NN + idx] = table[ri * NHEADS + h];
}

// ---------------- LN1 + shift + window partition for one chunk (fp32 out) ----------------
__global__ __launch_bounds__(256) void ln1_kernel(
    const float* __restrict__ x, const float* __restrict__ g,
    const float* __restrict__ bt, float* __restrict__ wins,
    int w0, int Mrows) {
    int t = blockIdx.x * 4 + (threadIdx.x >> 6);
    if (t >= Mrows) return;
    int lane = threadIdx.x & 63;
    int wl = t / NTOK, n = t - wl * NTOK;
    int tok = win_to_tok(w0 + wl, n);
    const float* xp = x + (size_t)tok * DIMC;
    float v0 = xp[lane], v1 = xp[lane + 64], v2 = xp[lane + 128];
    float s = v0 + v1 + v2, s2 = v0 * v0 + v1 * v1 + v2 * v2;
    #pragma unroll
    for (int m = 32; m >= 1; m >>= 1) { s += __shfl_xor(s, m, 64); s2 += __shfl_xor(s2, m, 64); }
    float mean = s * (1.f / 192.f);
    float var = s2 * (1.f / 192.f) - mean * mean;
    float r = rsqrtf(var + 1e-5f);
    float* op = wins + (size_t)t * DIMC;
    op[lane]       = (v0 - mean) * r * g[lane]       + bt[lane];
    op[lane + 64]  = (v1 - mean) * r * g[lane + 64]  + bt[lane + 64];
    op[lane + 128] = (v2 - mean) * r * g[lane + 128] + bt[lane + 128];
}

// ---------------- LN2 for one MLP chunk ----------------
__global__ __launch_bounds__(256) void ln2_kernel(
    const float* __restrict__ x2, const float* __restrict__ g,
    const float* __restrict__ bt, float* __restrict__ y, int r0g) {
    int t = blockIdx.x * 4 + (threadIdx.x >> 6);
    int lane = threadIdx.x & 63;
    const float* xp = x2 + (size_t)(r0g + t) * DIMC;
    float v0 = xp[lane], v1 = xp[lane + 64], v2 = xp[lane + 128];
    float s = v0 + v1 + v2, s2 = v0 * v0 + v1 * v1 + v2 * v2;
    #pragma unroll
    for (int m = 32; m >= 1; m >>= 1) { s += __shfl_xor(s, m, 64); s2 += __shfl_xor(s2, m, 64); }
    float mean = s * (1.f / 192.f);
    float var = s2 * (1.f / 192.f) - mean * mean;
    float r = rsqrtf(var + 1e-5f);
    float* op = y + (size_t)t * DIMC;
    op[lane]       = (v0 - mean) * r * g[lane]       + bt[lane];
    op[lane + 64]  = (v1 - mean) * r * g[lane + 64]  + bt[lane + 64];
    op[lane + 128] = (v2 - mean) * r * g[lane + 128] + bt[lane + 128];
}

// ---------------- tiled GEMM (fp32 VALU, unchanged from verified round 6) ----------------
template <int EPI, typename AT>
__global__ __launch_bounds__(256) void gemm_kernel(
    const AT* __restrict__ A, const float* __restrict__ Bw,
    const float* __restrict__ bias, int K, int Mrows, int w0, int r0g,
    const float* __restrict__ shortcut,
    float* __restrict__ xout,
    void* __restrict__ out_p) {
    __shared__ __align__(16) float As[16 * 64];
    __shared__ __align__(16) float Bs[16 * 64];
    int tid = threadIdx.x;
    int tx = tid & 15, ty = tid >> 4;
    int row0 = blockIdx.y * 64, col0 = blockIdx.x * 64;
    float acc[4][4];
    #pragma unroll
    for (int i = 0; i < 4; i++)
        #pragma unroll
        for (int j = 0; j < 4; j++) acc[i][j] = 0.f;
    int arow = tid >> 2, ak = (tid & 3) * 4;
    int ar = row0 + arow; if (ar >= Mrows) ar = Mrows - 1;
    for (int k0 = 0; k0 < K; k0 += 16) {
        const AT* ap = A + (size_t)ar * K + k0 + ak;
        const float* bp = Bw + (size_t)(col0 + arow) * K + k0 + ak;
        #pragma unroll
        for (int e = 0; e < 4; e++) As[(ak + e) * 64 + arow] = ldf(ap + e);
        #pragma unroll
        for (int e = 0; e < 4; e++) Bs[(ak + e) * 64 + arow] = bp[e];
        __syncthreads();
        #pragma unroll
        for (int kk = 0; kk < 16; kk++) {
            float4 a4 = *(const float4*)&As[kk * 64 + ty * 4];
            float4 b4 = *(const float4*)&Bs[kk * 64 + tx * 4];
            float a[4] = {a4.x, a4.y, a4.z, a4.w};
            float b[4] = {b4.x, b4.y, b4.z, b4.w};
            #pragma unroll
            for (int i = 0; i < 4; i++)
                #pragma unroll
                for (int j = 0; j < 4; j++) acc[i][j] += a[i] * b[j];
        }
        __syncthreads();
    }
    #pragma unroll
    for (int i = 0; i < 4; i++) {
        int r = row0 + ty * 4 + i;
        if (r >= Mrows) continue;
        #pragma unroll
        for (int j = 0; j < 4; j++) {
            int c = col0 + tx * 4 + j;
            float v = acc[i][j] + bias[c];
            if (EPI == 0) {
                int wl = r / NTOK, n = r - wl * NTOK;
                int t = c / DIMC, rem = c - t * DIMC;
                int hh = rem >> 5, d = rem & 31;
                if (t == 0) v *= QSCALE;
                ((__hip_bfloat16*)out_p)[((((size_t)wl * NHEADS + hh) * 3 + t) * NTOK + n) * HD + d] = f2b(v);
            } else if (EPI == 1) {
                int wl = r / NTOK, n = r - wl * NTOK;
                size_t tok = (size_t)win_to_tok(w0 + wl, n);
                xout[tok * DIMC + c] = v + shortcut[tok * DIMC + c];
            } else if (EPI == 2) {
                float gel = 0.5f * v * (1.0f + erff(v * 0.70710678118654752f));
                ((float*)out_p)[(size_t)r * MLP + c] = gel;
            } else {
                size_t gi = (size_t)(r0g + r) * DIMC + c;
                xout[gi] += v;
            }
        }
    }
}

// ---------------- MFMA attention ----------------
// grid (W*NHEADS, 11), block 128 (2 waves). Wave = one q-tile of 16.
// qkv chunk layout [wl][h][t][n][d] bf16. out fp32 R0[(wl*343+q)*192 + h*32+d].
// S^T = K·Q^T per 16x16 tile: A=K-frag, B=Q-frag (both contiguous row reads).
// softmax over m: per-lane regs + 2 shuffles (q = lane&15). P normalized, bf16,
// LDS round-trip [q][m] (b64 writes / b128 reads) -> A-operand of P·V.
__global__ __launch_bounds__(128) void attn_kernel(
    const __hip_bfloat16* __restrict__ qkv, const float* __restrict__ biasTT,
    const float* __restrict__ mask, float* __restrict__ out, int w0) {
    int wl = blockIdx.x / NHEADS, h = blockIdx.x - wl * NHEADS;
    int wm = (w0 + wl) & 63;
    __shared__ __align__(16) unsigned VtU[32][176];              // V^T bf16 [d][m], m padded 352
    __shared__ __align__(16) __hip_bfloat16 Pb[2][16][360];      // per-wave P [q][m]
    const __hip_bfloat16* base = qkv + ((size_t)(wl * NHEADS + h) * 3) * NTOK * HD;
    const __hip_bfloat16* Kp = base + NTOK * HD;
    const unsigned* Vp = (const unsigned*)(base + 2 * NTOK * HD);   // [m][dpair]
    // stage V^T: thread u handles (m-pair, d-pair)
    for (int u = threadIdx.x; u < 176 * 16; u += 128) {
        int m2 = u >> 4, dp = u & 15;
        unsigned a = 0, b = 0;
        if (m2 <= 170)      { a = Vp[(2 * m2) * 16 + dp]; b = Vp[(2 * m2 + 1) * 16 + dp]; }
        else if (m2 == 171) { a = Vp[342 * 16 + dp]; }
        VtU[2 * dp][m2]     = (a & 0xffffu) | (b << 16);
        VtU[2 * dp + 1][m2] = (a >> 16) | (b & 0xffff0000u);
    }
    __syncthreads();
    int wave = threadIdx.x >> 6, lane = threadIdx.x & 63;
    int quad = lane >> 4, r = lane & 15;
    int qt = blockIdx.y * 2 + wave;            // q-tile 0..21
    int q0 = qt * 16;
    int qc = q0 + r; if (qc > 342) qc = 342;   // clamped q for loads
    bf16x8 qf = *(const bf16x8*)(base + (size_t)qc * HD + quad * 8);
    const float* bb = biasTT + (size_t)h * NN + qc;
    const float* mb = mask + (size_t)wm * NN + qc;
    // ---- scores S^T tiles, kept in registers ----
    float S[22][4];
    #pragma unroll
    for (int mt = 0; mt < 22; mt++) {
        int mr = mt * 16 + r; if (mr > 342) mr = 342;
        bf16x8 kf = *(const bf16x8*)(Kp + (size_t)mr * HD + quad * 8);
        f32x4 c = {0.f, 0.f, 0.f, 0.f};
        c = __builtin_amdgcn_mfma_f32_16x16x32_bf16(kf, qf, c, 0, 0, 0);
        #pragma unroll
        for (int i = 0; i < 4; i++) {
            int m = mt * 16 + quad * 4 + i;
            S[mt][i] = (m < NTOK) ? (c[i] + bb[(size_t)m * NTOK] + mb[(size_t)m * NTOK]) : -1e30f;
        }
    }
    // ---- softmax over m (regs + cross-quad shuffles) ----
    float mx = -1e30f;
    #pragma unroll
    for (int mt = 0; mt < 22; mt++)
        #pragma unroll
        for (int i = 0; i < 4; i++) mx = fmaxf(mx, S[mt][i]);
    mx = fmaxf(mx, __shfl_xor(mx, 16, 64));
    mx = fmaxf(mx, __shfl_xor(mx, 32, 64));
    float l = 0.f;
    #pragma unroll
    for (int mt = 0; mt < 22; mt++)
        #pragma unroll
        for (int i = 0; i < 4; i++) { float p = __expf(S[mt][i] - mx); S[mt][i] = p; l += p; }
    l += __shfl_xor(l, 16, 64);
    l += __shfl_xor(l, 32, 64);
    float rl = 1.f / l;
    // ---- write normalized P (bf16) to LDS [q][m] ----
    __hip_bfloat16* prow = &Pb[wave][r][0];
    #pragma unroll
    for (int mt = 0; mt < 22; mt++) {
        unsigned u0 = (unsigned)bfu(S[mt][0] * rl) | ((unsigned)bfu(S[mt][1] * rl) << 16);
        unsigned u1 = (unsigned)bfu(S[mt][2] * rl) | ((unsigned)bfu(S[mt][3] * rl) << 16);
        *(uint2*)(prow + mt * 16 + quad * 4) = make_uint2(u0, u1);
    }
    __builtin_amdgcn_s_waitcnt(0);  // lgkmcnt(0): own-wave LDS writes visible (no barrier needed)
    // ---- O = P·V via mfma, two d-halves ----
    const __hip_bfloat16* vt = (const __hip_bfloat16*)&VtU[0][0];
    f32x4 o0 = {0.f, 0.f, 0.f, 0.f}, o1 = {0.f, 0.f, 0.f, 0.f};
    #pragma unroll
    for (int ch = 0; ch < 11; ch++) {
        bf16x8 pf = *(const bf16x8*)(&Pb[wave][r][ch * 32 + quad * 8]);
        bf16x8 v0 = *(const bf16x8*)(vt + (size_t)r * 352 + ch * 32 + quad * 8);
        bf16x8 v1 = *(const bf16x8*)(vt + (size_t)(r + 16) * 352 + ch * 32 + quad * 8);
        o0 = __builtin_amdgcn_mfma_f32_16x16x32_bf16(pf, v0, o0, 0, 0, 0);
        o1 = __builtin_amdgcn_mfma_f32_16x16x32_bf16(pf, v1, o1, 0, 0, 0);
    }
    // ---- store: C layout row = q-local = quad*4+reg, col = d = r ----
    #pragma unroll
    for (int i = 0; i < 4; i++) {
        int q = q0 + quad * 4 + i;
        if (q < NTOK) {
            float* orow = out + ((size_t)wl * NTOK + q) * DIMC + h * HD;
            orow[r] = o0[i];
            orow[r + 16] = o1[i];
        }
    }
}

extern "C" void kernel_launch(void* const* d_in, const int* in_sizes, int n_in,
                              void* d_out, int out_size, void* d_ws, size_t ws_size,
                              hipStream_t stream) {
    const float* x      = (const float*)d_in[0];
    const float* mask   = (const float*)d_in[1];
    const int*   relidx = (const int*)d_in[2];
    const float* table  = (const float*)d_in[3];
    const float* n1g    = (const float*)d_in[4];
    const float* n1b    = (const float*)d_in[5];
    const float* qkv_w  = (const float*)d_in[6];
    const float* qkv_b  = (const float*)d_in[7];
    const float* proj_w = (const float*)d_in[8];
    const float* proj_b = (const float*)d_in[9];
    const float* n2g    = (const float*)d_in[10];
    const float* n2b    = (const float*)d_in[11];
    const float* fc1_w  = (const float*)d_in[12];
    const float* fc1_b  = (const float*)d_in[13];
    const float* fc2_w  = (const float*)d_in[14];
    const float* fc2_b  = (const float*)d_in[15];

    char* ws = (char*)d_ws;
    float* biasTT = (float*)ws;
    float* out = (float*)d_out;          // fp32 output == residual stream x2

    // attention: W windows/chunk; per window: R0 fp32 263,424 B + qkv bf16 395,136 B
    int W = 1;
    {
        const int cand[7] = {64, 32, 16, 8, 4, 2, 1};
        for (int i = 0; i < 7; i++) {
            if ((size_t)WS_AFTER_BIAS + (size_t)cand[i] * 658560 <= ws_size) { W = cand[i]; break; }
        }
    }
    int R = 64;
    {
        const int cand[6] = {6272, 3136, 896, 448, 128, 64};
        for (int i = 0; i < 6; i++) {
            if ((size_t)WS_AFTER_BIAS + (size_t)cand[i] * 3840 <= ws_size) { R = cand[i]; break; }
        }
    }
    float*          R0  = (float*)(ws + WS_AFTER_BIAS);
    __hip_bfloat16* QKV = (__hip_bfloat16*)(ws + WS_AFTER_BIAS + (size_t)W * 263424);
    float*          Y   = (float*)(ws + WS_AFTER_BIAS);
    float*          HID = (float*)(ws + WS_AFTER_BIAS + (size_t)R * 768);

    bias_kernel<<<(NN + 255) / 256, 256, 0, stream>>>(relidx, table, biasTT);

    int mch = W * NTOK;
    int gy = (mch + 63) / 64;
    int gln = (mch + 3) / 4;
    for (int c = 0; c < 128 / W; c++) {
        int w0 = c * W;
        ln1_kernel<<<gln, 256, 0, stream>>>(x, n1g, n1b, R0, w0, mch);
        gemm_kernel<0, float><<<dim3(9, gy), 256, 0, stream>>>(
            R0, qkv_w, qkv_b, DIMC, mch, w0, 0, nullptr, nullptr, QKV);
        attn_kernel<<<dim3(W * NHEADS, 11), 128, 0, stream>>>(QKV, biasTT, mask, R0, w0);
        gemm_kernel<1, float><<<dim3(3, gy), 256, 0, stream>>>(
            R0, proj_w, proj_b, DIMC, mch, w0, 0, x, out, nullptr);
    }
    for (int m = 0; m < MTOT / R; m++) {
        int r0g = m * R;
        ln2_kernel<<<R / 4, 256, 0, stream>>>(out, n2g, n2b, Y, r0g);
        gemm_kernel<2, float><<<dim3(12, R / 64), 256, 0, stream>>>(
            Y, fc1_w, fc1_b, DIMC, R, 0, 0, nullptr, nullptr, HID);
        gemm_kernel<3, float><<<dim3(3, R / 64), 256, 0, stream>>>(
            HID, fc2_w, fc2_b, MLP, R, 0, r0g, nullptr, out, nullptr);
    }
}

// Round 8
// 638.407 us; speedup vs baseline: 6.6908x; 2.0740x over previous
//
#include <hip/hip_runtime.h>
#include <hip/hip_bf16.h>
#include <math.h>

// ---- problem constants ----
#define DIMC 192
#define NTOK 343
#define NHEADS 6
#define HD 32
#define NN 117649           // NTOK*NTOK
#define MLP 768
#define MTOT 43904
#define QSCALE 0.17677669529663687f

// ---- ws fixed regions ----
#define WS_WGT    1411840             // after bf16 biasTT[6][343][343] (1,411,788 B padded)
#define OFF_QKVW  0
#define OFF_PROJW 110592
#define OFF_FC1W  147456
#define OFF_FC2W  294912
#define NWGT      442368
#define WS_CHUNK  2296576             // WS_WGT + 884,736

typedef __attribute__((ext_vector_type(8))) short bf16x8;
typedef __attribute__((ext_vector_type(4))) float f32x4;

__device__ __forceinline__ float b2f(__hip_bfloat16 v) { return __bfloat162float(v); }
__device__ __forceinline__ __hip_bfloat16 f2b(float v) { return __float2bfloat16(v); }
__device__ __forceinline__ unsigned short bfu(float v) {
    __hip_bfloat16 b = f2b(v);
    return *(unsigned short*)&b;
}

// (global window, token-in-window) -> linear token index in x (handles cyclic shift)
__device__ __forceinline__ int win_to_tok(int w, int n) {
    int bb = w >> 6, widx = w & 63;
    int wd = widx >> 4, wh = (widx >> 2) & 3, ww = widx & 3;
    int sd = n / 49, r = n - sd * 49;
    int sh = r / 7, sw = r - sh * 7;
    int gd = wd * 7 + sd + 3; if (gd >= 28) gd -= 28;
    int gh = wh * 7 + sh + 3; if (gh >= 28) gh -= 28;
    int gw = ww * 7 + sw + 3; if (gw >= 28) gw -= 28;
    return bb * 21952 + gd * 784 + gh * 28 + gw;
}

// Swin shift-mask region id for (window widx 0..63, token n): label from unshifted coords
__device__ __forceinline__ int region_of(int widx, int n) {
    int wd = widx >> 4, wh = (widx >> 2) & 3, ww = widx & 3;
    int sd = n / 49, rr = n - sd * 49;
    int sh = rr / 7, sw = rr - sh * 7;
    int cd = wd * 7 + sd, ch = wh * 7 + sh, cw = ww * 7 + sw;
    int dsl = (cd < 21) ? 0 : ((cd < 25) ? 1 : 2);
    int hsl = (ch < 21) ? 0 : ((ch < 25) ? 1 : 2);
    int wsl = (cw < 21) ? 0 : ((cw < 25) ? 1 : 2);
    return dsl * 9 + hsl * 3 + wsl;
}

// ---------------- rel-position bias, transposed, bf16: biasTT[h][m][q] ----------------
__global__ __launch_bounds__(256) void bias_kernel(
    const int* __restrict__ rel, const float* __restrict__ table,
    __hip_bfloat16* __restrict__ biasTT) {
    int idx = blockIdx.x * 256 + threadIdx.x;   // idx = m*343 + q
    if (idx >= NN) return;
    int m = idx / NTOK, q = idx - m * NTOK;
    int ri = rel[q * NTOK + m];
    #pragma unroll
    for (int h = 0; h < NHEADS; h++)
        biasTT[(size_t)h * NN + idx] = f2b(table[ri * NHEADS + h]);
}

// ---------------- weights fp32 -> bf16 ----------------
__global__ __launch_bounds__(256) void wconv_kernel(
    const float* __restrict__ qkv_w, const float* __restrict__ proj_w,
    const float* __restrict__ fc1_w, const float* __restrict__ fc2_w,
    __hip_bfloat16* __restrict__ Wb) {
    int i = blockIdx.x * 256 + threadIdx.x;
    if (i >= NWGT) return;
    float v;
    if      (i < OFF_PROJW) v = qkv_w[i - OFF_QKVW];
    else if (i < OFF_FC1W)  v = proj_w[i - OFF_PROJW];
    else if (i < OFF_FC2W)  v = fc1_w[i - OFF_FC1W];
    else                    v = fc2_w[i - OFF_FC2W];
    Wb[i] = f2b(v);
}

// ---------------- LN1 + shift + window partition (bf16 out) ----------------
__global__ __launch_bounds__(256) void ln1_kernel(
    const float* __restrict__ x, const float* __restrict__ g,
    const float* __restrict__ bt, __hip_bfloat16* __restrict__ wins,
    int w0, int Mrows) {
    int t = blockIdx.x * 4 + (threadIdx.x >> 6);
    if (t >= Mrows) return;
    int lane = threadIdx.x & 63;
    int wl = t / NTOK, n = t - wl * NTOK;
    int tok = win_to_tok(w0 + wl, n);
    const float* xp = x + (size_t)tok * DIMC;
    float v0 = xp[lane], v1 = xp[lane + 64], v2 = xp[lane + 128];
    float s = v0 + v1 + v2, s2 = v0 * v0 + v1 * v1 + v2 * v2;
    #pragma unroll
    for (int m = 32; m >= 1; m >>= 1) { s += __shfl_xor(s, m, 64); s2 += __shfl_xor(s2, m, 64); }
    float mean = s * (1.f / 192.f);
    float var = s2 * (1.f / 192.f) - mean * mean;
    float r = rsqrtf(var + 1e-5f);
    __hip_bfloat16* op = wins + (size_t)t * DIMC;
    op[lane]       = f2b((v0 - mean) * r * g[lane]       + bt[lane]);
    op[lane + 64]  = f2b((v1 - mean) * r * g[lane + 64]  + bt[lane + 64]);
    op[lane + 128] = f2b((v2 - mean) * r * g[lane + 128] + bt[lane + 128]);
}

// ---------------- LN2 (fp32 x2 in from d_out, bf16 out) ----------------
__global__ __launch_bounds__(256) void ln2_kernel(
    const float* __restrict__ x2, const float* __restrict__ g,
    const float* __restrict__ bt, __hip_bfloat16* __restrict__ y, int r0g) {
    int t = blockIdx.x * 4 + (threadIdx.x >> 6);
    int lane = threadIdx.x & 63;
    const float* xp = x2 + (size_t)(r0g + t) * DIMC;
    float v0 = xp[lane], v1 = xp[lane + 64], v2 = xp[lane + 128];
    float s = v0 + v1 + v2, s2 = v0 * v0 + v1 * v1 + v2 * v2;
    #pragma unroll
    for (int m = 32; m >= 1; m >>= 1) { s += __shfl_xor(s, m, 64); s2 += __shfl_xor(s2, m, 64); }
    float mean = s * (1.f / 192.f);
    float var = s2 * (1.f / 192.f) - mean * mean;
    float r = rsqrtf(var + 1e-5f);
    __hip_bfloat16* op = y + (size_t)t * DIMC;
    op[lane]       = f2b((v0 - mean) * r * g[lane]       + bt[lane]);
    op[lane + 64]  = f2b((v1 - mean) * r * g[lane + 64]  + bt[lane + 64]);
    op[lane + 128] = f2b((v2 - mean) * r * g[lane + 128] + bt[lane + 128]);
}

// ---------------- MFMA GEMM: C[Mrows,N] = A[Mrows,K](bf16) * W[N,K]^T(bf16) + bias(fp32) ----------------
// block 256 = 4 waves; tile M=256 (wave = 64 rows), N=64; BK=32; 16x16x32 bf16 MFMA.
// EPI 0: qkv scatter (+q scale) -> bf16 qkv    1: proj + shortcut -> fp32 d_out (token scatter)
//     2: GELU -> bf16 hid                      3: + x2(d_out) -> fp32 d_out in place
template <int EPI>
__global__ __launch_bounds__(256) void gemm_kernel(
    const __hip_bfloat16* __restrict__ A, const __hip_bfloat16* __restrict__ Bw,
    const float* __restrict__ bias, int K, int Mrows, int w0, int r0g,
    const float* __restrict__ shortcut, float* __restrict__ xout,
    void* __restrict__ out_p) {
    __shared__ __align__(16) __hip_bfloat16 As[256 * 32];
    __shared__ __align__(16) __hip_bfloat16 Bs[64 * 32];
    int tid = threadIdx.x;
    int wave = tid >> 6, lane = tid & 63;
    int quad = lane >> 4, r = lane & 15;
    int row0 = blockIdx.y * 256, col0 = blockIdx.x * 64;
    int lrow = lane >> 2, lcol = (lane & 3) * 8;
    f32x4 acc[4][4];
    #pragma unroll
    for (int mi = 0; mi < 4; mi++)
        #pragma unroll
        for (int ni = 0; ni < 4; ni++) acc[mi][ni] = (f32x4){0.f, 0.f, 0.f, 0.f};
    for (int k0 = 0; k0 < K; k0 += 32) {
        // stage A: wave stages its own 64 rows (4 insts of 16 rows)
        #pragma unroll
        for (int inst = 0; inst < 4; inst++) {
            int rowl = wave * 64 + inst * 16 + lrow;
            int ar = row0 + rowl; if (ar >= Mrows) ar = Mrows - 1;
            *(uint4*)&As[rowl * 32 + lcol] = *(const uint4*)(A + (size_t)ar * K + k0 + lcol);
        }
        // stage B: wave w stages rows w*16..w*16+15
        {
            int rowb = wave * 16 + lrow;
            *(uint4*)&Bs[rowb * 32 + lcol] = *(const uint4*)(Bw + (size_t)(col0 + rowb) * K + k0 + lcol);
        }
        __syncthreads();
        bf16x8 af[4], bf[4];
        #pragma unroll
        for (int mi = 0; mi < 4; mi++)
            af[mi] = *(const bf16x8*)&As[(wave * 64 + mi * 16 + r) * 32 + quad * 8];
        #pragma unroll
        for (int ni = 0; ni < 4; ni++)
            bf[ni] = *(const bf16x8*)&Bs[(ni * 16 + r) * 32 + quad * 8];
        #pragma unroll
        for (int mi = 0; mi < 4; mi++)
            #pragma unroll
            for (int ni = 0; ni < 4; ni++)
                acc[mi][ni] = __builtin_amdgcn_mfma_f32_16x16x32_bf16(af[mi], bf[ni], acc[mi][ni], 0, 0, 0);
        __syncthreads();
    }
    #pragma unroll
    for (int mi = 0; mi < 4; mi++) {
        #pragma unroll
        for (int i = 0; i < 4; i++) {
            int rloc = wave * 64 + mi * 16 + quad * 4 + i;   // C row = first operand row
            int rr = row0 + rloc;
            if (rr >= Mrows) continue;
            #pragma unroll
            for (int ni = 0; ni < 4; ni++) {
                int c = col0 + ni * 16 + r;                  // C col = second operand row
                float v = acc[mi][ni][i] + bias[c];
                if (EPI == 0) {
                    int wl = rr / NTOK, n = rr - wl * NTOK;
                    int t = c / DIMC, rem = c - t * DIMC;
                    int hh = rem >> 5, d = rem & 31;
                    if (t == 0) v *= QSCALE;
                    ((__hip_bfloat16*)out_p)[((((size_t)wl * NHEADS + hh) * 3 + t) * NTOK + n) * HD + d] = f2b(v);
                } else if (EPI == 1) {
                    int wl = rr / NTOK, n = rr - wl * NTOK;
                    size_t tok = (size_t)win_to_tok(w0 + wl, n);
                    xout[tok * DIMC + c] = v + shortcut[tok * DIMC + c];
                } else if (EPI == 2) {
                    float gel = 0.5f * v * (1.0f + erff(v * 0.70710678118654752f));
                    ((__hip_bfloat16*)out_p)[(size_t)rr * MLP + c] = f2b(gel);
                } else {
                    size_t gi = (size_t)(r0g + rr) * DIMC + c;
                    xout[gi] += v;
                }
            }
        }
    }
}

// ---------------- MFMA attention (mask computed in-kernel, bias bf16) ----------------
// grid (W*NHEADS, 11), block 128 (2 waves). Wave = one q-tile of 16.
__global__ __launch_bounds__(128) void attn_kernel(
    const __hip_bfloat16* __restrict__ qkv, const __hip_bfloat16* __restrict__ biasTT,
    __hip_bfloat16* __restrict__ out, int w0) {
    int wl = blockIdx.x / NHEADS, h = blockIdx.x - wl * NHEADS;
    int wm = (w0 + wl) & 63;
    __shared__ __align__(16) unsigned VtU[32 * 180];             // V^T bf16 [d][m], row stride 360 bf16
    __shared__ __align__(16) __hip_bfloat16 Pb[2][16][360];      // per-wave P [q][m]
    __shared__ unsigned char regS[NTOK];                         // shift-mask region per token
    const __hip_bfloat16* base = qkv + ((size_t)(wl * NHEADS + h) * 3) * NTOK * HD;
    const __hip_bfloat16* Kp = base + NTOK * HD;
    const unsigned* Vp = (const unsigned*)(base + 2 * NTOK * HD);   // [m][dpair]
    for (int i = threadIdx.x; i < NTOK; i += 128) regS[i] = (unsigned char)region_of(wm, i);
    // stage V^T: thread u handles (m-pair, d-pair); global reads coalesced over dp
    for (int u = threadIdx.x; u < 176 * 16; u += 128) {
        int m2 = u >> 4, dp = u & 15;
        unsigned a = 0, b = 0;
        if (m2 <= 170)      { a = Vp[(2 * m2) * 16 + dp]; b = Vp[(2 * m2 + 1) * 16 + dp]; }
        else if (m2 == 171) { a = Vp[342 * 16 + dp]; }
        VtU[(2 * dp) * 180 + m2]     = (a & 0xffffu) | (b << 16);
        VtU[(2 * dp + 1) * 180 + m2] = (a >> 16) | (b & 0xffff0000u);
    }
    __syncthreads();
    int wave = threadIdx.x >> 6, lane = threadIdx.x & 63;
    int quad = lane >> 4, r = lane & 15;
    int qt = blockIdx.y * 2 + wave;            // q-tile 0..21
    int q0 = qt * 16;
    int qc = q0 + r; if (qc > 342) qc = 342;
    bf16x8 qf = *(const bf16x8*)(base + (size_t)qc * HD + quad * 8);
    const __hip_bfloat16* bb = biasTT + (size_t)h * NN + qc;
    int rq = regS[qc];
    // ---- S^T tiles in registers ----
    float S[22][4];
    #pragma unroll
    for (int mt = 0; mt < 22; mt++) {
        int mr = mt * 16 + r; if (mr > 342) mr = 342;
        bf16x8 kf = *(const bf16x8*)(Kp + (size_t)mr * HD + quad * 8);
        f32x4 c = {0.f, 0.f, 0.f, 0.f};
        c = __builtin_amdgcn_mfma_f32_16x16x32_bf16(kf, qf, c, 0, 0, 0);
        #pragma unroll
        for (int i = 0; i < 4; i++) {
            int m = mt * 16 + quad * 4 + i;
            if (m < NTOK) {
                float msk = (regS[m] == rq) ? 0.f : -100.f;
                S[mt][i] = c[i] + b2f(bb[(size_t)m * NTOK]) + msk;
            } else S[mt][i] = -1e30f;
        }
    }
    // ---- softmax over m ----
    float mx = -1e30f;
    #pragma unroll
    for (int mt = 0; mt < 22; mt++)
        #pragma unroll
        for (int i = 0; i < 4; i++) mx = fmaxf(mx, S[mt][i]);
    mx = fmaxf(mx, __shfl_xor(mx, 16, 64));
    mx = fmaxf(mx, __shfl_xor(mx, 32, 64));
    float l = 0.f;
    #pragma unroll
    for (int mt = 0; mt < 22; mt++)
        #pragma unroll
        for (int i = 0; i < 4; i++) { float p = __expf(S[mt][i] - mx); S[mt][i] = p; l += p; }
    l += __shfl_xor(l, 16, 64);
    l += __shfl_xor(l, 32, 64);
    float rl = 1.f / l;
    // ---- write normalized P (bf16) to LDS [q][m] ----
    __hip_bfloat16* prow = &Pb[wave][r][0];
    #pragma unroll
    for (int mt = 0; mt < 22; mt++) {
        unsigned u0 = (unsigned)bfu(S[mt][0] * rl) | ((unsigned)bfu(S[mt][1] * rl) << 16);
        unsigned u1 = (unsigned)bfu(S[mt][2] * rl) | ((unsigned)bfu(S[mt][3] * rl) << 16);
        *(uint2*)(prow + mt * 16 + quad * 4) = make_uint2(u0, u1);
    }
    __builtin_amdgcn_s_waitcnt(0);  // lgkmcnt(0): own-wave LDS writes visible
    // ---- O = P·V ----
    const __hip_bfloat16* vt = (const __hip_bfloat16*)&VtU[0];
    f32x4 o0 = {0.f, 0.f, 0.f, 0.f}, o1 = {0.f, 0.f, 0.f, 0.f};
    #pragma unroll
    for (int ch = 0; ch < 11; ch++) {
        bf16x8 pf = *(const bf16x8*)(&Pb[wave][r][ch * 32 + quad * 8]);
        bf16x8 v0 = *(const bf16x8*)(vt + (size_t)r * 360 + ch * 32 + quad * 8);
        bf16x8 v1 = *(const bf16x8*)(vt + (size_t)(r + 16) * 360 + ch * 32 + quad * 8);
        o0 = __builtin_amdgcn_mfma_f32_16x16x32_bf16(pf, v0, o0, 0, 0, 0);
        o1 = __builtin_amdgcn_mfma_f32_16x16x32_bf16(pf, v1, o1, 0, 0, 0);
    }
    #pragma unroll
    for (int i = 0; i < 4; i++) {
        int q = q0 + quad * 4 + i;
        if (q < NTOK) {
            __hip_bfloat16* orow = out + ((size_t)wl * NTOK + q) * DIMC + h * HD;
            orow[r] = f2b(o0[i]);
            orow[r + 16] = f2b(o1[i]);
        }
    }
}

extern "C" void kernel_launch(void* const* d_in, const int* in_sizes, int n_in,
                              void* d_out, int out_size, void* d_ws, size_t ws_size,
                              hipStream_t stream) {
    const float* x      = (const float*)d_in[0];
    const int*   relidx = (const int*)d_in[2];
    const float* table  = (const float*)d_in[3];
    const float* n1g    = (const float*)d_in[4];
    const float* n1b    = (const float*)d_in[5];
    const float* qkv_w  = (const float*)d_in[6];
    const float* qkv_b  = (const float*)d_in[7];
    const float* proj_w = (const float*)d_in[8];
    const float* proj_b = (const float*)d_in[9];
    const float* n2g    = (const float*)d_in[10];
    const float* n2b    = (const float*)d_in[11];
    const float* fc1_w  = (const float*)d_in[12];
    const float* fc1_b  = (const float*)d_in[13];
    const float* fc2_w  = (const float*)d_in[14];
    const float* fc2_b  = (const float*)d_in[15];

    char* ws = (char*)d_ws;
    __hip_bfloat16* biasTT = (__hip_bfloat16*)ws;
    __hip_bfloat16* Wb     = (__hip_bfloat16*)(ws + WS_WGT);
    float* out = (float*)d_out;          // fp32 output == residual stream x2

    // ---- ws-adaptive chunks ----
    // attention: W windows/chunk; per window: R0 bf16 131,712 B + qkv bf16 395,136 B
    int W = 1;
    {
        const int cand[7] = {64, 32, 16, 8, 4, 2, 1};
        for (int i = 0; i < 7; i++)
            if ((size_t)WS_CHUNK + (size_t)cand[i] * 526848 <= ws_size) { W = cand[i]; break; }
    }
    // mlp: R rows/chunk; per row: Y bf16 384 B + hid bf16 1536 B
    int R = 64;
    {
        const int cand[9] = {43904, 21952, 10976, 6272, 3136, 896, 448, 128, 64};
        for (int i = 0; i < 9; i++)
            if ((size_t)WS_CHUNK + (size_t)cand[i] * 1920 <= ws_size) { R = cand[i]; break; }
    }
    __hip_bfloat16* R0  = (__hip_bfloat16*)(ws + WS_CHUNK);
    __hip_bfloat16* QKV = (__hip_bfloat16*)(ws + WS_CHUNK + (size_t)W * 131712);
    __hip_bfloat16* Y   = (__hip_bfloat16*)(ws + WS_CHUNK);
    __hip_bfloat16* HID = (__hip_bfloat16*)(ws + WS_CHUNK + (size_t)R * 384);

    bias_kernel<<<(NN + 255) / 256, 256, 0, stream>>>(relidx, table, biasTT);
    wconv_kernel<<<(NWGT + 255) / 256, 256, 0, stream>>>(qkv_w, proj_w, fc1_w, fc2_w, Wb);

    // ---- attention path ----
    int mch = W * NTOK;
    int gy = (mch + 255) / 256;
    int gln = (mch + 3) / 4;
    for (int c = 0; c < 128 / W; c++) {
        int w0 = c * W;
        ln1_kernel<<<gln, 256, 0, stream>>>(x, n1g, n1b, R0, w0, mch);
        gemm_kernel<0><<<dim3(9, gy), 256, 0, stream>>>(
            R0, Wb + OFF_QKVW, qkv_b, DIMC, mch, w0, 0, nullptr, nullptr, QKV);
        attn_kernel<<<dim3(W * NHEADS, 11), 128, 0, stream>>>(QKV, biasTT, R0, w0);
        gemm_kernel<1><<<dim3(3, gy), 256, 0, stream>>>(
            R0, Wb + OFF_PROJW, proj_b, DIMC, mch, w0, 0, x, out, nullptr);
    }
    // ---- MLP path ----
    for (int m = 0; m < MTOT / R; m++) {
        int r0g = m * R;
        int gyr = (R + 255) / 256;
        ln2_kernel<<<R / 4, 256, 0, stream>>>(out, n2g, n2b, Y, r0g);
        gemm_kernel<2><<<dim3(12, gyr), 256, 0, stream>>>(
            Y, Wb + OFF_FC1W, fc1_b, DIMC, R, 0, 0, nullptr, nullptr, HID);
        gemm_kernel<3><<<dim3(3, gyr), 256, 0, stream>>>(
            HID, Wb + OFF_FC2W, fc2_b, MLP, R, 0, r0g, nullptr, out, nullptr);
    }
}

// Round 9
// 488.383 us; speedup vs baseline: 8.7461x; 1.3072x over previous
//
#include <hip/hip_runtime.h>
#include <hip/hip_bf16.h>
#include <math.h>

// ---- problem constants ----
#define DIMC 192
#define NTOK 343
#define NHEADS 6
#define HD 32
#define NN 117649           // NTOK*NTOK
#define MLP 768
#define MTOT 43904
#define QSCALE 0.17677669529663687f

// ---- ws fixed regions ----
// biasQ[h][88][344][4] bf16 = 6*88*344*4*2 = 1,453,056 B
#define WS_WGT    1453056
#define OFF_QKVW  0
#define OFF_PROJW 110592
#define OFF_FC1W  147456
#define OFF_FC2W  294912
#define NWGT      442368
#define WS_CHUNK  2337792             // WS_WGT + 884,736

typedef __attribute__((ext_vector_type(8))) short bf16x8;
typedef __attribute__((ext_vector_type(4))) float f32x4;

__device__ __forceinline__ float b2f(__hip_bfloat16 v) { return __bfloat162float(v); }
__device__ __forceinline__ __hip_bfloat16 f2b(float v) { return __float2bfloat16(v); }
__device__ __forceinline__ unsigned short bfu(float v) {
    __hip_bfloat16 b = f2b(v);
    return *(unsigned short*)&b;
}

__device__ __forceinline__ float2 bfp2(unsigned u) {
    union { unsigned i; float f; } a, b;
    a.i = u << 16;
    b.i = u & 0xffff0000u;
    return make_float2(a.f, b.f);
}

// (global window, token-in-window) -> linear token index in x (handles cyclic shift)
__device__ __forceinline__ int win_to_tok(int w, int n) {
    int bb = w >> 6, widx = w & 63;
    int wd = widx >> 4, wh = (widx >> 2) & 3, ww = widx & 3;
    int sd = n / 49, r = n - sd * 49;
    int sh = r / 7, sw = r - sh * 7;
    int gd = wd * 7 + sd + 3; if (gd >= 28) gd -= 28;
    int gh = wh * 7 + sh + 3; if (gh >= 28) gh -= 28;
    int gw = ww * 7 + sw + 3; if (gw >= 28) gw -= 28;
    return bb * 21952 + gd * 784 + gh * 28 + gw;
}

// Swin shift-mask region id for (window widx 0..63, token n)
__device__ __forceinline__ int region_of(int widx, int n) {
    int wd = widx >> 4, wh = (widx >> 2) & 3, ww = widx & 3;
    int sd = n / 49, rr = n - sd * 49;
    int sh = rr / 7, sw = rr - sh * 7;
    int cd = wd * 7 + sd, ch = wh * 7 + sh, cw = ww * 7 + sw;
    int dsl = (cd < 21) ? 0 : ((cd < 25) ? 1 : 2);
    int hsl = (ch < 21) ? 0 : ((ch < 25) ? 1 : 2);
    int wsl = (cw < 21) ? 0 : ((cw < 25) ? 1 : 2);
    return dsl * 9 + hsl * 3 + wsl;
}

// ---------------- rel-position bias, A-frag-friendly: biasQ[h][m>>2][q][m&3] bf16 ----------------
__global__ __launch_bounds__(256) void bias_kernel(
    const int* __restrict__ rel, const float* __restrict__ table,
    __hip_bfloat16* __restrict__ biasQ) {
    int idx = blockIdx.x * 256 + threadIdx.x;   // idx = m*343 + q
    if (idx >= NN) return;
    int m = idx / NTOK, q = idx - m * NTOK;
    int ri = rel[q * NTOK + m];
    #pragma unroll
    for (int h = 0; h < NHEADS; h++)
        biasQ[(((size_t)h * 88 + (m >> 2)) * 344 + q) * 4 + (m & 3)] = f2b(table[ri * NHEADS + h]);
}

// ---------------- weights fp32 -> bf16 ----------------
__global__ __launch_bounds__(256) void wconv_kernel(
    const float* __restrict__ qkv_w, const float* __restrict__ proj_w,
    const float* __restrict__ fc1_w, const float* __restrict__ fc2_w,
    __hip_bfloat16* __restrict__ Wb) {
    int i = blockIdx.x * 256 + threadIdx.x;
    if (i >= NWGT) return;
    float v;
    if      (i < OFF_PROJW) v = qkv_w[i - OFF_QKVW];
    else if (i < OFF_FC1W)  v = proj_w[i - OFF_PROJW];
    else if (i < OFF_FC2W)  v = fc1_w[i - OFF_FC1W];
    else                    v = fc2_w[i - OFF_FC2W];
    Wb[i] = f2b(v);
}

// ---------------- LN1 + shift + window partition (bf16 out) ----------------
__global__ __launch_bounds__(256) void ln1_kernel(
    const float* __restrict__ x, const float* __restrict__ g,
    const float* __restrict__ bt, __hip_bfloat16* __restrict__ wins,
    int w0, int Mrows) {
    int t = blockIdx.x * 4 + (threadIdx.x >> 6);
    if (t >= Mrows) return;
    int lane = threadIdx.x & 63;
    int wl = t / NTOK, n = t - wl * NTOK;
    int tok = win_to_tok(w0 + wl, n);
    const float* xp = x + (size_t)tok * DIMC;
    float v0 = xp[lane], v1 = xp[lane + 64], v2 = xp[lane + 128];
    float s = v0 + v1 + v2, s2 = v0 * v0 + v1 * v1 + v2 * v2;
    #pragma unroll
    for (int m = 32; m >= 1; m >>= 1) { s += __shfl_xor(s, m, 64); s2 += __shfl_xor(s2, m, 64); }
    float mean = s * (1.f / 192.f);
    float var = s2 * (1.f / 192.f) - mean * mean;
    float r = rsqrtf(var + 1e-5f);
    __hip_bfloat16* op = wins + (size_t)t * DIMC;
    op[lane]       = f2b((v0 - mean) * r * g[lane]       + bt[lane]);
    op[lane + 64]  = f2b((v1 - mean) * r * g[lane + 64]  + bt[lane + 64]);
    op[lane + 128] = f2b((v2 - mean) * r * g[lane + 128] + bt[lane + 128]);
}

// ---------------- LN2 (fp32 x2 in from d_out, bf16 out) ----------------
__global__ __launch_bounds__(256) void ln2_kernel(
    const float* __restrict__ x2, const float* __restrict__ g,
    const float* __restrict__ bt, __hip_bfloat16* __restrict__ y, int r0g) {
    int t = blockIdx.x * 4 + (threadIdx.x >> 6);
    int lane = threadIdx.x & 63;
    const float* xp = x2 + (size_t)(r0g + t) * DIMC;
    float v0 = xp[lane], v1 = xp[lane + 64], v2 = xp[lane + 128];
    float s = v0 + v1 + v2, s2 = v0 * v0 + v1 * v1 + v2 * v2;
    #pragma unroll
    for (int m = 32; m >= 1; m >>= 1) { s += __shfl_xor(s, m, 64); s2 += __shfl_xor(s2, m, 64); }
    float mean = s * (1.f / 192.f);
    float var = s2 * (1.f / 192.f) - mean * mean;
    float r = rsqrtf(var + 1e-5f);
    __hip_bfloat16* op = y + (size_t)t * DIMC;
    op[lane]       = f2b((v0 - mean) * r * g[lane]       + bt[lane]);
    op[lane + 64]  = f2b((v1 - mean) * r * g[lane + 64]  + bt[lane + 64]);
    op[lane + 128] = f2b((v2 - mean) * r * g[lane + 128] + bt[lane + 128]);
}

// ---------------- MFMA GEMM (unchanged from verified round 8) ----------------
template <int EPI>
__global__ __launch_bounds__(256) void gemm_kernel(
    const __hip_bfloat16* __restrict__ A, const __hip_bfloat16* __restrict__ Bw,
    const float* __restrict__ bias, int K, int Mrows, int w0, int r0g,
    const float* __restrict__ shortcut, float* __restrict__ xout,
    void* __restrict__ out_p) {
    __shared__ __align__(16) __hip_bfloat16 As[256 * 32];
    __shared__ __align__(16) __hip_bfloat16 Bs[64 * 32];
    int tid = threadIdx.x;
    int wave = tid >> 6, lane = tid & 63;
    int quad = lane >> 4, r = lane & 15;
    int row0 = blockIdx.y * 256, col0 = blockIdx.x * 64;
    int lrow = lane >> 2, lcol = (lane & 3) * 8;
    f32x4 acc[4][4];
    #pragma unroll
    for (int mi = 0; mi < 4; mi++)
        #pragma unroll
        for (int ni = 0; ni < 4; ni++) acc[mi][ni] = (f32x4){0.f, 0.f, 0.f, 0.f};
    for (int k0 = 0; k0 < K; k0 += 32) {
        #pragma unroll
        for (int inst = 0; inst < 4; inst++) {
            int rowl = wave * 64 + inst * 16 + lrow;
            int ar = row0 + rowl; if (ar >= Mrows) ar = Mrows - 1;
            *(uint4*)&As[rowl * 32 + lcol] = *(const uint4*)(A + (size_t)ar * K + k0 + lcol);
        }
        {
            int rowb = wave * 16 + lrow;
            *(uint4*)&Bs[rowb * 32 + lcol] = *(const uint4*)(Bw + (size_t)(col0 + rowb) * K + k0 + lcol);
        }
        __syncthreads();
        bf16x8 af[4], bf[4];
        #pragma unroll
        for (int mi = 0; mi < 4; mi++)
            af[mi] = *(const bf16x8*)&As[(wave * 64 + mi * 16 + r) * 32 + quad * 8];
        #pragma unroll
        for (int ni = 0; ni < 4; ni++)
            bf[ni] = *(const bf16x8*)&Bs[(ni * 16 + r) * 32 + quad * 8];
        #pragma unroll
        for (int mi = 0; mi < 4; mi++)
            #pragma unroll
            for (int ni = 0; ni < 4; ni++)
                acc[mi][ni] = __builtin_amdgcn_mfma_f32_16x16x32_bf16(af[mi], bf[ni], acc[mi][ni], 0, 0, 0);
        __syncthreads();
    }
    #pragma unroll
    for (int mi = 0; mi < 4; mi++) {
        #pragma unroll
        for (int i = 0; i < 4; i++) {
            int rloc = wave * 64 + mi * 16 + quad * 4 + i;
            int rr = row0 + rloc;
            if (rr >= Mrows) continue;
            #pragma unroll
            for (int ni = 0; ni < 4; ni++) {
                int c = col0 + ni * 16 + r;
                float v = acc[mi][ni][i] + bias[c];
                if (EPI == 0) {
                    int wl = rr / NTOK, n = rr - wl * NTOK;
                    int t = c / DIMC, rem = c - t * DIMC;
                    int hh = rem >> 5, d = rem & 31;
                    if (t == 0) v *= QSCALE;
                    ((__hip_bfloat16*)out_p)[((((size_t)wl * NHEADS + hh) * 3 + t) * NTOK + n) * HD + d] = f2b(v);
                } else if (EPI == 1) {
                    int wl = rr / NTOK, n = rr - wl * NTOK;
                    size_t tok = (size_t)win_to_tok(w0 + wl, n);
                    xout[tok * DIMC + c] = v + shortcut[tok * DIMC + c];
                } else if (EPI == 2) {
                    float gel = 0.5f * v * (1.0f + erff(v * 0.70710678118654752f));
                    ((__hip_bfloat16*)out_p)[(size_t)rr * MLP + c] = f2b(gel);
                } else {
                    size_t gi = (size_t)(r0g + rr) * DIMC + c;
                    xout[gi] += v;
                }
            }
        }
    }
}

// ---------------- MFMA attention v2: one block (4 waves) per (window, head) ----------------
// Each wave loops q-tiles qt = wave, wave+4, ... (22 tiles). V^T staged once in LDS.
// P transform S^T(C-layout) -> A-frag via cross-quad __shfl (no LDS, no barrier).
__global__ __launch_bounds__(256) void attn_kernel(
    const __hip_bfloat16* __restrict__ qkv, const __hip_bfloat16* __restrict__ biasQ,
    __hip_bfloat16* __restrict__ out, int w0) {
    int wl = blockIdx.x / NHEADS, h = blockIdx.x - wl * NHEADS;
    int wm = (w0 + wl) & 63;
    __shared__ __align__(16) unsigned VtU[32 * 180];   // V^T bf16 [d][m], row stride 360 el
    __shared__ unsigned char regS[NTOK];
    const __hip_bfloat16* base = qkv + ((size_t)(wl * NHEADS + h) * 3) * NTOK * HD;
    const __hip_bfloat16* Kp = base + NTOK * HD;
    const unsigned* Vp = (const unsigned*)(base + 2 * NTOK * HD);   // [m][dpair]
    int tid = threadIdx.x;
    for (int i = tid; i < NTOK; i += 256) regS[i] = (unsigned char)region_of(wm, i);
    for (int u = tid; u < 176 * 16; u += 256) {
        int m2 = u >> 4, dp = u & 15;
        unsigned a = 0, b = 0;
        if (m2 <= 170)      { a = Vp[(2 * m2) * 16 + dp]; b = Vp[(2 * m2 + 1) * 16 + dp]; }
        else if (m2 == 171) { a = Vp[342 * 16 + dp]; }
        VtU[(2 * dp) * 180 + m2]     = (a & 0xffffu) | (b << 16);
        VtU[(2 * dp + 1) * 180 + m2] = (a >> 16) | (b & 0xffff0000u);
    }
    __syncthreads();
    int wave = tid >> 6, lane = tid & 63;
    int quad = lane >> 4, r = lane & 15;
    const __hip_bfloat16* vt = (const __hip_bfloat16*)&VtU[0];
    for (int qt = wave; qt < 22; qt += 4) {
        int q0 = qt * 16;
        int qc = q0 + r; if (qc > 342) qc = 342;
        bf16x8 qf = *(const bf16x8*)(base + (size_t)qc * HD + quad * 8);
        int rq = regS[qc];
        // ---- S^T tiles in registers ----
        float S[22][4];
        #pragma unroll
        for (int mt = 0; mt < 22; mt++) {
            int mr = mt * 16 + r; if (mr > 342) mr = 342;
            bf16x8 kf = *(const bf16x8*)(Kp + (size_t)mr * HD + quad * 8);
            f32x4 c = {0.f, 0.f, 0.f, 0.f};
            c = __builtin_amdgcn_mfma_f32_16x16x32_bf16(kf, qf, c, 0, 0, 0);
            uint2 bu = *(const uint2*)(biasQ + (((size_t)h * 88 + mt * 4 + quad) * 344 + qc) * 4);
            float2 blo = bfp2(bu.x), bhi = bfp2(bu.y);
            float bv[4] = {blo.x, blo.y, bhi.x, bhi.y};
            #pragma unroll
            for (int i = 0; i < 4; i++) {
                int m = mt * 16 + quad * 4 + i;
                if (m < NTOK) {
                    float msk = (regS[m] == rq) ? 0.f : -100.f;
                    S[mt][i] = c[i] + bv[i] + msk;
                } else S[mt][i] = -1e30f;
            }
        }
        // ---- softmax over m ----
        float mx = -1e30f;
        #pragma unroll
        for (int mt = 0; mt < 22; mt++)
            #pragma unroll
            for (int i = 0; i < 4; i++) mx = fmaxf(mx, S[mt][i]);
        mx = fmaxf(mx, __shfl_xor(mx, 16, 64));
        mx = fmaxf(mx, __shfl_xor(mx, 32, 64));
        float l = 0.f;
        #pragma unroll
        for (int mt = 0; mt < 22; mt++)
            #pragma unroll
            for (int i = 0; i < 4; i++) { float p = __expf(S[mt][i] - mx); S[mt][i] = p; l += p; }
        l += __shfl_xor(l, 16, 64);
        l += __shfl_xor(l, 32, 64);
        float rl = 1.f / l;
        // ---- pack normalized P into 2 uints per tile (reuse S[mt][0..1]) ----
        int Pn[22][2];
        #pragma unroll
        for (int mt = 0; mt < 22; mt++) {
            Pn[mt][0] = (int)((unsigned)bfu(S[mt][0] * rl) | ((unsigned)bfu(S[mt][1] * rl) << 16));
            Pn[mt][1] = (int)((unsigned)bfu(S[mt][2] * rl) | ((unsigned)bfu(S[mt][3] * rl) << 16));
        }
        // ---- O = P·V: A-frag built by cross-quad shuffles ----
        f32x4 o0 = {0.f, 0.f, 0.f, 0.f}, o1 = {0.f, 0.f, 0.f, 0.f};
        bool hiQuad = (quad >= 2);
        int srcBase = (quad & 1) * 32 + r;
        #pragma unroll
        for (int ch = 0; ch < 11; ch++) {
            unsigned afu[4];
            #pragma unroll
            for (int k = 0; k < 4; k++) {
                int src = srcBase + (k >> 1) * 16;
                int lo = __shfl(Pn[2 * ch][k & 1], src, 64);
                int hi = __shfl(Pn[2 * ch + 1][k & 1], src, 64);
                afu[k] = (unsigned)(hiQuad ? hi : lo);
            }
            bf16x8 pf = *(bf16x8*)afu;
            bf16x8 v0 = *(const bf16x8*)(vt + (size_t)r * 360 + ch * 32 + quad * 8);
            bf16x8 v1 = *(const bf16x8*)(vt + (size_t)(r + 16) * 360 + ch * 32 + quad * 8);
            o0 = __builtin_amdgcn_mfma_f32_16x16x32_bf16(pf, v0, o0, 0, 0, 0);
            o1 = __builtin_amdgcn_mfma_f32_16x16x32_bf16(pf, v1, o1, 0, 0, 0);
        }
        #pragma unroll
        for (int i = 0; i < 4; i++) {
            int q = q0 + quad * 4 + i;
            if (q < NTOK) {
                __hip_bfloat16* orow = out + ((size_t)wl * NTOK + q) * DIMC + h * HD;
                orow[r] = f2b(o0[i]);
                orow[r + 16] = f2b(o1[i]);
            }
        }
    }
}

extern "C" void kernel_launch(void* const* d_in, const int* in_sizes, int n_in,
                              void* d_out, int out_size, void* d_ws, size_t ws_size,
                              hipStream_t stream) {
    const float* x      = (const float*)d_in[0];
    const int*   relidx = (const int*)d_in[2];
    const float* table  = (const float*)d_in[3];
    const float* n1g    = (const float*)d_in[4];
    const float* n1b    = (const float*)d_in[5];
    const float* qkv_w  = (const float*)d_in[6];
    const float* qkv_b  = (const float*)d_in[7];
    const float* proj_w = (const float*)d_in[8];
    const float* proj_b = (const float*)d_in[9];
    const float* n2g    = (const float*)d_in[10];
    const float* n2b    = (const float*)d_in[11];
    const float* fc1_w  = (const float*)d_in[12];
    const float* fc1_b  = (const float*)d_in[13];
    const float* fc2_w  = (const float*)d_in[14];
    const float* fc2_b  = (const float*)d_in[15];

    char* ws = (char*)d_ws;
    __hip_bfloat16* biasQ = (__hip_bfloat16*)ws;
    __hip_bfloat16* Wb    = (__hip_bfloat16*)(ws + WS_WGT);
    float* out = (float*)d_out;          // fp32 output == residual stream x2

    // ---- ws-adaptive chunks ----
    int W = 1;
    {
        const int cand[7] = {64, 32, 16, 8, 4, 2, 1};
        for (int i = 0; i < 7; i++)
            if ((size_t)WS_CHUNK + (size_t)cand[i] * 526848 <= ws_size) { W = cand[i]; break; }
    }
    int R = 64;
    {
        const int cand[9] = {43904, 21952, 10976, 6272, 3136, 896, 448, 128, 64};
        for (int i = 0; i < 9; i++)
            if ((size_t)WS_CHUNK + (size_t)cand[i] * 1920 <= ws_size) { R = cand[i]; break; }
    }
    __hip_bfloat16* R0  = (__hip_bfloat16*)(ws + WS_CHUNK);
    __hip_bfloat16* QKV = (__hip_bfloat16*)(ws + WS_CHUNK + (size_t)W * 131712);
    __hip_bfloat16* Y   = (__hip_bfloat16*)(ws + WS_CHUNK);
    __hip_bfloat16* HID = (__hip_bfloat16*)(ws + WS_CHUNK + (size_t)R * 384);

    bias_kernel<<<(NN + 255) / 256, 256, 0, stream>>>(relidx, table, biasQ);
    wconv_kernel<<<(NWGT + 255) / 256, 256, 0, stream>>>(qkv_w, proj_w, fc1_w, fc2_w, Wb);

    // ---- attention path ----
    int mch = W * NTOK;
    int gy = (mch + 255) / 256;
    int gln = (mch + 3) / 4;
    for (int c = 0; c < 128 / W; c++) {
        int w0 = c * W;
        ln1_kernel<<<gln, 256, 0, stream>>>(x, n1g, n1b, R0, w0, mch);
        gemm_kernel<0><<<dim3(9, gy), 256, 0, stream>>>(
            R0, Wb + OFF_QKVW, qkv_b, DIMC, mch, w0, 0, nullptr, nullptr, QKV);
        attn_kernel<<<W * NHEADS, 256, 0, stream>>>(QKV, biasQ, R0, w0);
        gemm_kernel<1><<<dim3(3, gy), 256, 0, stream>>>(
            R0, Wb + OFF_PROJW, proj_b, DIMC, mch, w0, 0, x, out, nullptr);
    }
    // ---- MLP path ----
    for (int m = 0; m < MTOT / R; m++) {
        int r0g = m * R;
        int gyr = (R + 255) / 256;
        ln2_kernel<<<R / 4, 256, 0, stream>>>(out, n2g, n2b, Y, r0g);
        gemm_kernel<2><<<dim3(12, gyr), 256, 0, stream>>>(
            Y, Wb + OFF_FC1W, fc1_b, DIMC, R, 0, 0, nullptr, nullptr, HID);
        gemm_kernel<3><<<dim3(3, gyr), 256, 0, stream>>>(
            HID, Wb + OFF_FC2W, fc2_b, MLP, R, 0, r0g, nullptr, out, nullptr);
    }
}